// Round 14
// baseline (214.568 us; speedup 1.0000x reference)
//
#include <hip/hip_runtime.h>
#include <hip/hip_bf16.h>
#include <math.h>

#define S_LEN 2048
#define HIDW 2048
#define NHEAD 16
#define NKVH 4
#define HD 128
#define NB 2
#define MROWS (NB * S_LEN)                 // 4096
#define QKVN (NHEAD * HD + 2 * NKVH * HD)  // 3072
#define KOFF (NHEAD * HD)                  // 2048
#define VOFF (NHEAD * HD + NKVH * HD)      // 2560

typedef __bf16 bf16_t;
typedef __bf16 bf16x4_t __attribute__((ext_vector_type(4)));
typedef __bf16 bf16x8_t __attribute__((ext_vector_type(8)));
typedef float f32x4_t __attribute__((ext_vector_type(4)));

__device__ __forceinline__ void gload_lds16(const bf16_t* g, bf16_t* l) {
  __builtin_amdgcn_global_load_lds(
      (const __attribute__((address_space(1))) void*)g,
      (__attribute__((address_space(3))) void*)l, 16, 0, 0);
}

__device__ __forceinline__ f32x4_t zero4() {
  f32x4_t z = {0.f, 0.f, 0.f, 0.f};
  return z;
}

__device__ __forceinline__ float fexp2(float x) {
#if __has_builtin(__builtin_amdgcn_exp2f)
  return __builtin_amdgcn_exp2f(x);
#else
  return exp2f(x);
#endif
}

// ---------------- convert x (f32 -> bf16), 8 elems/thread ----------------
__global__ __launch_bounds__(256) void k_cvt8(const float* __restrict__ in,
                                              bf16_t* __restrict__ out, int n8) {
  int i = blockIdx.x * 256 + threadIdx.x;
  if (i >= n8) return;
  const float4* p = (const float4*)(in + (size_t)i * 8);
  float4 a = p[0], b = p[1];
  bf16x8_t r;
  r[0] = (bf16_t)a.x; r[1] = (bf16_t)a.y; r[2] = (bf16_t)a.z; r[3] = (bf16_t)a.w;
  r[4] = (bf16_t)b.x; r[5] = (bf16_t)b.y; r[6] = (bf16_t)b.z; r[7] = (bf16_t)b.w;
  *(bf16x8_t*)(out + (size_t)i * 8) = r;
}

// ---------------- transpose + convert: in f32 [R][C] -> out bf16 [C][R] ----
__global__ __launch_bounds__(256) void k_tr_cvt(const float* __restrict__ in,
                                                bf16_t* __restrict__ out, int R, int C) {
  __shared__ float t[32][33];
  int c0 = blockIdx.x * 32, r0 = blockIdx.y * 32;
  int tx = threadIdx.x & 31, ty = threadIdx.x >> 5;
#pragma unroll
  for (int rr = ty; rr < 32; rr += 8) t[rr][tx] = in[(size_t)(r0 + rr) * C + c0 + tx];
  __syncthreads();
#pragma unroll
  for (int rr = ty; rr < 32; rr += 8)
    out[(size_t)(c0 + rr) * R + r0 + tx] = (bf16_t)t[tx][rr];
}

// ---------------- GEMM BMx256 tile (BM = BMH*128), BK=64, 8 waves ----------
// ONE barrier per K-tile, distance-1 prefetch, race-free: tile t+1's DMAs go
// to buffer (t+1)&1 which is read-complete since the last barrier (different
// buffer from the one being consumed). Waves FREE-RUN within the tile body
// (no per-phase barriers: ds_reads hit a stable buffer, MFMAs use own regs),
// so one wave's MFMA covers another's ds_read drain — the m97/m114 implicit
// overlap that the phase-locked R13 schedule destroyed (22% MfmaUtil).
// Fragment reads interleave with MFMA blocks: af0+b01 / blk1 / b23 / blk2 /
// (BMH2: af1 / blk3 blk4). Boundary: vmcnt(0) (t+1 issued a full tile ago)
// + s_barrier.
// EPI=0: f32 out. EPI=2: fused rope epilogue (cos/sin staged in dead LDS).
template <int EPI, int BMH>
__global__ __launch_bounds__(512, 2) void k_gemm256(const bf16_t* __restrict__ A,
                                                    const bf16_t* __restrict__ Bt,
                                                    void* __restrict__ Cout,
                                                    int M, int N, int K, int nby,
                                                    const float* __restrict__ cosT,
                                                    const float* __restrict__ sinT) {
  __shared__ bf16_t As[2][BMH * 128 * 64];
  __shared__ bf16_t Bs[2][256 * 64];

  int tid = threadIdx.x;
  int lane = tid & 63, wid = tid >> 6;
  int l15 = lane & 15, lg = lane >> 4;
  int wrb = (wid >> 2) * (BMH * 64);  // wave M-offset (2 M-halves)
  int wcb = (wid & 3) * 64;           // wave N-offset (4 N-quarters)

  int nwg = gridDim.x;
  int qx = nwg >> 3;
  int lin = blockIdx.x;
  int wg = (lin & 7) * qx + (lin >> 3);
  int row0 = (wg / nby) * (BMH * 128), col0 = (wg % nby) * 256;

  int srow = tid >> 3;
  int scol = ((tid & 7) ^ (srow & 7)) * 8;
  const bf16_t* Ag = A + (size_t)(row0 + srow) * K + scol;
  const bf16_t* Bg = Bt + (size_t)(col0 + srow) * K + scol;

  f32x4_t acc[BMH * 4][4];
#pragma unroll
  for (int i = 0; i < BMH * 4; i++)
#pragma unroll
    for (int j = 0; j < 4; j++) acc[i][j] = zero4();

  int xr = (l15 & 7) << 4;
  int nk = K >> 6;

  auto stA = [&](int tt, int u) {
    gload_lds16(Ag + (size_t)u * 64 * K + (size_t)tt * 64,
                As[tt & 1] + u * 4096 + tid * 8);
  };
  auto stB = [&](int tt, int u) {
    gload_lds16(Bg + (size_t)u * 64 * K + (size_t)tt * 64,
                Bs[tt & 1] + u * 4096 + tid * 8);
  };

  // prologue: stage tile 0, full drain
  for (int u = 0; u < BMH * 2; u++) stA(0, u);
  for (int u = 0; u < 4; u++) stB(0, u);
  asm volatile("s_waitcnt vmcnt(0)" ::: "memory");
  __builtin_amdgcn_s_barrier();

  for (int t = 0; t < nk; t++) {
    const char* Ac = (const char*)As[t & 1];
    const char* Bc = (const char*)Bs[t & 1];
    // issue next tile's DMA into the OTHER buffer (read-complete since the
    // last barrier -> no hazard); stays in flight across the whole tile body
    if (t + 1 < nk) {
#pragma unroll
      for (int u = 0; u < BMH * 2; u++) stA(t + 1, u);
#pragma unroll
      for (int u = 0; u < 4; u++) stB(t + 1, u);
    }

    // frags: af0 + b01
    bf16x8_t af0[4][2], b01[2][2];
#pragma unroll
    for (int i = 0; i < 4; i++) {
      int row = wrb + i * 16 + l15;
#pragma unroll
      for (int kk = 0; kk < 2; kk++)
        af0[i][kk] = *(const bf16x8_t*)(Ac + ((row * 128 + kk * 64 + lg * 16) ^ xr));
    }
#pragma unroll
    for (int j = 0; j < 2; j++) {
      int rowb = wcb + j * 16 + l15;
#pragma unroll
      for (int kk = 0; kk < 2; kk++)
        b01[j][kk] = *(const bf16x8_t*)(Bc + ((rowb * 128 + kk * 64 + lg * 16) ^ xr));
    }
    // blk1: af0 x b01
    __builtin_amdgcn_s_setprio(1);
#pragma unroll
    for (int i = 0; i < 4; i++)
#pragma unroll
      for (int j = 0; j < 2; j++)
#pragma unroll
        for (int kk = 0; kk < 2; kk++)
          acc[i][j] = __builtin_amdgcn_mfma_f32_16x16x32_bf16(af0[i][kk], b01[j][kk],
                                                              acc[i][j], 0, 0, 0);
    __builtin_amdgcn_s_setprio(0);

    // frags: b23 (read under blk1's pipe drain)
    bf16x8_t b23[2][2];
#pragma unroll
    for (int j = 0; j < 2; j++) {
      int rowb = wcb + (2 + j) * 16 + l15;
#pragma unroll
      for (int kk = 0; kk < 2; kk++)
        b23[j][kk] = *(const bf16x8_t*)(Bc + ((rowb * 128 + kk * 64 + lg * 16) ^ xr));
    }
    // blk2: af0 x b23
    __builtin_amdgcn_s_setprio(1);
#pragma unroll
    for (int i = 0; i < 4; i++)
#pragma unroll
      for (int j = 0; j < 2; j++)
#pragma unroll
        for (int kk = 0; kk < 2; kk++)
          acc[i][2 + j] = __builtin_amdgcn_mfma_f32_16x16x32_bf16(
              af0[i][kk], b23[j][kk], acc[i][2 + j], 0, 0, 0);
    __builtin_amdgcn_s_setprio(0);

    if constexpr (BMH == 2) {
      // frags: af1 (read under blk2's pipe drain)
      bf16x8_t af1[4][2];
#pragma unroll
      for (int i = 0; i < 4; i++) {
        int row = wrb + 64 + i * 16 + l15;
#pragma unroll
        for (int kk = 0; kk < 2; kk++)
          af1[i][kk] = *(const bf16x8_t*)(Ac + ((row * 128 + kk * 64 + lg * 16) ^ xr));
      }
      // blk3 + blk4: af1 x b01, af1 x b23
      __builtin_amdgcn_s_setprio(1);
#pragma unroll
      for (int i = 0; i < 4; i++)
#pragma unroll
        for (int j = 0; j < 2; j++)
#pragma unroll
          for (int kk = 0; kk < 2; kk++)
            acc[4 + i][j] = __builtin_amdgcn_mfma_f32_16x16x32_bf16(
                af1[i][kk], b01[j][kk], acc[4 + i][j], 0, 0, 0);
#pragma unroll
      for (int i = 0; i < 4; i++)
#pragma unroll
        for (int j = 0; j < 2; j++)
#pragma unroll
          for (int kk = 0; kk < 2; kk++)
            acc[4 + i][2 + j] = __builtin_amdgcn_mfma_f32_16x16x32_bf16(
                af1[i][kk], b23[j][kk], acc[4 + i][2 + j], 0, 0, 0);
      __builtin_amdgcn_s_setprio(0);
    }

    // boundary: next tile's DMA (issued a full tile ago) must be in LDS
    if (t + 1 < nk) asm volatile("s_waitcnt vmcnt(0)" ::: "memory");
    __builtin_amdgcn_s_barrier();
  }

  if (EPI == 2) {
    if (col0 < VOFF) {
      // stage cos/sin rows [sbase, sbase+256) x 64 f32 into dead As/Bs LDS
      int sbase = row0 & (S_LEN - 1);  // rows never straddle the 2048 boundary
      bf16_t* cosL = &As[0][0];
      bf16_t* sinL = &Bs[0][0];
#pragma unroll
      for (int k = 0; k < 8; k++) {
        gload_lds16((const bf16_t*)(cosT + (size_t)sbase * 64 + k * 2048 + tid * 4),
                    cosL + k * 4096 + tid * 8);
        gload_lds16((const bf16_t*)(sinT + (size_t)sbase * 64 + k * 2048 + tid * 4),
                    sinL + k * 4096 + tid * 8);
      }
      asm volatile("s_waitcnt vmcnt(0)" ::: "memory");
      __builtin_amdgcn_s_barrier();
      const float* cosF = (const float*)cosL;
      const float* sinF = (const float*)sinL;
      const float QS = 0.08838834764831845f * 1.4426950408889634f;
#pragma unroll
      for (int i = 0; i < BMH * 4; i++) {
#pragma unroll
        for (int j = 0; j < 4; j++) {
          int c = col0 + wcb + j * 16 + l15;
          int rlb = wrb + i * 16 + lg * 4;
          float scale = (c < KOFF) ? QS : 1.0f;
          int p0 = (c & 127) >> 1;
          int codd = c & 1;
#pragma unroll
          for (int qd = 0; qd < 4; qd++) {
            int rl = rlb + qd;
            float self = acc[i][j][qd];
            float other = __shfl_xor(self, 1);
            float cv = cosF[rl * 64 + p0], sv = sinF[rl * 64 + p0];
            float outv = codd ? (self * cv + other * sv) : (self * cv - other * sv);
            ((bf16_t*)Cout)[(size_t)(row0 + rl) * N + c] = (bf16_t)(outv * scale);
          }
        }
      }
    } else {
      // pure-V block: plain bf16 store (transpose done by k_vt)
#pragma unroll
      for (int i = 0; i < BMH * 4; i++) {
#pragma unroll
        for (int j = 0; j < 4; j++) {
          int r = row0 + wrb + i * 16 + lg * 4;
          int c = col0 + wcb + j * 16 + l15;
#pragma unroll
          for (int qd = 0; qd < 4; qd++)
            ((bf16_t*)Cout)[(size_t)(r + qd) * N + c] = (bf16_t)acc[i][j][qd];
        }
      }
    }
  } else {
#pragma unroll
    for (int i = 0; i < BMH * 4; i++) {
#pragma unroll
      for (int j = 0; j < 4; j++) {
        int r = row0 + wrb + i * 16 + lg * 4;
        int c = col0 + wcb + j * 16 + l15;
#pragma unroll
        for (int qd = 0; qd < 4; qd++)
          ((float*)Cout)[(size_t)(r + qd) * N + c] = acc[i][j][qd];
      }
    }
  }
}

// ---------------- V -> Vt relayout: vt[b][kvh][d][s] -----------------------
__global__ __launch_bounds__(256) void k_vt(const bf16_t* __restrict__ qkv,
                                            bf16_t* __restrict__ vt) {
  __shared__ bf16_t t[32][33];
  int s0 = blockIdx.x * 32;
  int dt = (blockIdx.y & 3) * 32;
  int h = blockIdx.y >> 2;
  int b = blockIdx.z;
  int tx = threadIdx.x & 31, ty = threadIdx.x >> 5;
#pragma unroll
  for (int rr = ty; rr < 32; rr += 8)
    t[rr][tx] = qkv[(size_t)(b * S_LEN + s0 + rr) * QKVN + VOFF + h * HD + dt + tx];
  __syncthreads();
#pragma unroll
  for (int rr = ty; rr < 32; rr += 8)
    vt[((size_t)((b * NKVH + h) * HD + dt + rr)) * S_LEN + s0 + tx] = t[tx][rr];
}

// ---------------- flash attention: 4 waves, QBLK=64, 2-phase pipeline ------
// R8 structure + swapped QK^T softmax (R12, verified): mfma(K,Q) -> per-lane
// q-row stats, 4 shuffles/tile instead of 32.
__global__ __launch_bounds__(256, 2) void k_attn(const bf16_t* __restrict__ qkv,
                                                 const bf16_t* __restrict__ vt,
                                                 bf16_t* __restrict__ ctx) {
  __shared__ bf16_t Ks[2 * 64 * 128];   // 2 x 16 KB, swizzled [kv][d]
  __shared__ bf16_t Vs[2 * 128 * 64];   // 2 x 16 KB, swizzled [d][kv]
  __shared__ bf16_t plds[4][16 * 72];

  int tid = threadIdx.x;
  int lane = tid & 63, wid = tid >> 6;
  int idx = blockIdx.x;
  int bh = idx & 31;
  int qg = 31 - (idx >> 5);        // longest-first dispatch (LPT backfill)
  int b = bh >> 4, h = bh & 15;
  int kvh = h >> 2;
  int q0 = qg * 64 + wid * 16;
  int l15 = lane & 15, lg = lane >> 4;

  const bf16_t* Kbase = qkv + (size_t)(b * S_LEN) * QKVN + KOFF + kvh * HD;
  const bf16_t* Vbase = vt + (size_t)(b * NKVH + kvh) * HD * S_LEN;

  const bf16_t* Qp = qkv + (size_t)(b * S_LEN + q0 + l15) * QKVN + h * HD + lg * 8;
  bf16x8_t aq[4];
#pragma unroll
  for (int kk = 0; kk < 4; kk++) aq[kk] = *(const bf16x8_t*)(Qp + kk * 32);

  int Ls[4], Lk[4], Lv[4];
#pragma unroll
  for (int u = 0; u < 4; u++) {
    int L = u * 4096 + tid * 16;
    Ls[u] = L >> 1;
    Lk[u] = L ^ (((L >> 8) & 7) << 4);
    Lv[u] = L ^ (((L >> 7) & 7) << 4);
  }

  f32x4_t o[8];
#pragma unroll
  for (int j = 0; j < 8; j++) o[j] = zero4();
  float ms = -INFINITY, lsum = 0.f;   // per-lane scalars: stats of q-row l15

  bf16_t* pbuf = &plds[wid][0];
  int xr = (l15 & 7) << 4;
  int ntiles = qg + 1;
  int qcol = q0 + l15;                // this lane's q-row

#pragma unroll
  for (int u = 0; u < 4; u++) {
    gload_lds16(Kbase + (size_t)(Lk[u] >> 8) * QKVN + ((Lk[u] & 255) >> 1), Ks + Ls[u]);
    gload_lds16(Vbase + (size_t)(Lv[u] >> 7) * S_LEN + ((Lv[u] & 127) >> 1), Vs + Ls[u]);
  }
  __syncthreads();

  for (int t = 0; t < ntiles; t++) {
    int kv0 = t * 64;
    if (t + 1 < ntiles) {
      const bf16_t* Kn = Kbase + (size_t)(kv0 + 64) * QKVN;
      const bf16_t* Vn = Vbase + kv0 + 64;
      int bo = ((t + 1) & 1) * 8192;
#pragma unroll
      for (int u = 0; u < 4; u++) {
        gload_lds16(Kn + (size_t)(Lk[u] >> 8) * QKVN + ((Lk[u] & 255) >> 1), Ks + bo + Ls[u]);
        gload_lds16(Vn + (size_t)(Lv[u] >> 7) * S_LEN + ((Lv[u] & 127) >> 1), Vs + bo + Ls[u]);
      }
    }
    const char* Kb = (const char*)Ks + (t & 1) * 16384;
    const char* Vb = (const char*)Vs + (t & 1) * 16384;

    // ---- QK^T swapped: sacc[cg][i] = S[kv = kv0+cg*16+lg*4+i][q = qcol] ----
    f32x4_t sacc[4];
#pragma unroll
    for (int cg = 0; cg < 4; cg++) sacc[cg] = zero4();
#pragma unroll
    for (int cg = 0; cg < 4; cg++) {
#pragma unroll
      for (int kk = 0; kk < 4; kk++) {
        int boff = ((cg * 16 + l15) * 256 + kk * 64 + lg * 16) ^ xr;
        bf16x8_t bk = *(const bf16x8_t*)(Kb + boff);
        sacc[cg] = __builtin_amdgcn_mfma_f32_16x16x32_bf16(bk, aq[kk], sacc[cg], 0, 0, 0);
      }
    }
    if (kv0 + 63 > q0) {
#pragma unroll
      for (int cg = 0; cg < 4; cg++) {
#pragma unroll
        for (int i = 0; i < 4; i++) {
          int kvg = kv0 + cg * 16 + lg * 4 + i;
          if (kvg > qcol) sacc[cg][i] = -1e30f;
        }
      }
    }
    // ---- online softmax: in-lane reduce + 2 shuffles ----
    float pmax = sacc[0][0];
#pragma unroll
    for (int cg = 0; cg < 4; cg++)
#pragma unroll
      for (int i = 0; i < 4; i++) pmax = fmaxf(pmax, sacc[cg][i]);
    pmax = fmaxf(pmax, __shfl_xor(pmax, 16));
    pmax = fmaxf(pmax, __shfl_xor(pmax, 32));
    if (__any(pmax - ms > 8.0f)) {
      float nm = fmaxf(ms, pmax);
      float sc = fexp2(ms - nm);
      ms = nm;
      lsum *= sc;
      float sci[4];
#pragma unroll
      for (int i = 0; i < 4; i++) sci[i] = __shfl(sc, lg * 4 + i);
#pragma unroll
      for (int j = 0; j < 8; j++)
#pragma unroll
        for (int i = 0; i < 4; i++) o[j][i] *= sci[i];
    }
    float ls = 0.f;
#pragma unroll
    for (int cg = 0; cg < 4; cg++)
#pragma unroll
      for (int i = 0; i < 4; i++) {
        sacc[cg][i] = fexp2(sacc[cg][i] - ms);
        ls += sacc[cg][i];
      }
    ls += __shfl_xor(ls, 16);
    ls += __shfl_xor(ls, 32);
    lsum += ls;
    // ---- P -> per-wave LDS (row = q = l15; same contents as before) ----
#pragma unroll
    for (int cg = 0; cg < 4; cg++)
#pragma unroll
      for (int i = 0; i < 4; i++)
        pbuf[l15 * 72 + cg * 16 + lg * 4 + i] = (bf16_t)sacc[cg][i];
    __builtin_amdgcn_wave_barrier();
    bf16x8_t pa0 = *(const bf16x8_t*)(pbuf + l15 * 72 + lg * 8);
    bf16x8_t pa1 = *(const bf16x8_t*)(pbuf + l15 * 72 + 32 + lg * 8);
    __builtin_amdgcn_wave_barrier();
#pragma unroll
    for (int j = 0; j < 8; j++) {
      int d = j * 16 + l15;
      int bo0 = (d * 128 + lg * 16) ^ xr;
      int bo1 = (d * 128 + 64 + lg * 16) ^ xr;
      o[j] = __builtin_amdgcn_mfma_f32_16x16x32_bf16(
          pa0, *(const bf16x8_t*)(Vb + bo0), o[j], 0, 0, 0);
      o[j] = __builtin_amdgcn_mfma_f32_16x16x32_bf16(
          pa1, *(const bf16x8_t*)(Vb + bo1), o[j], 0, 0, 0);
    }
    __syncthreads();
  }

  bf16_t* Cp = ctx + (size_t)(b * S_LEN + q0) * KOFF + h * HD;
#pragma unroll
  for (int i = 0; i < 4; i++) {
    float inv = 1.f / __shfl(lsum, lg * 4 + i);
    int row = lg * 4 + i;
#pragma unroll
    for (int j = 0; j < 8; j++)
      Cp[(size_t)row * KOFF + j * 16 + l15] = (bf16_t)(o[j][i] * inv);
  }
}

extern "C" void kernel_launch(void* const* d_in, const int* in_sizes, int n_in,
                              void* d_out, int out_size, void* d_ws, size_t ws_size,
                              hipStream_t stream) {
  const float* x = (const float*)d_in[0];
  const float* wq = (const float*)d_in[1];
  const float* wk = (const float*)d_in[2];
  const float* wv = (const float*)d_in[3];
  const float* wo = (const float*)d_in[4];
  const float* cosT = (const float*)d_in[5];
  const float* sinT = (const float*)d_in[6];

  bf16_t* xb = (bf16_t*)d_ws;                          // 4096x2048 (later reused as ctx)
  bf16_t* wqkvT = xb + (size_t)MROWS * HIDW;           // 3072x2048
  bf16_t* woT = wqkvT + (size_t)QKVN * HIDW;           // 2048x2048
  bf16_t* qkv = woT + (size_t)HIDW * HIDW;             // 4096x3072
  bf16_t* vtb = qkv + (size_t)MROWS * QKVN;            // 2*4*128*2048

  // 1) convert x
  k_cvt8<<<MROWS * HIDW / 8 / 256, 256, 0, stream>>>(x, xb, MROWS * HIDW / 8);
  // 2) weight transposes (f32 -> bf16, [K][N] -> [N][K])
  k_tr_cvt<<<dim3(KOFF / 32, HIDW / 32), 256, 0, stream>>>(wq, wqkvT, HIDW, KOFF);
  k_tr_cvt<<<dim3((NKVH * HD) / 32, HIDW / 32), 256, 0, stream>>>(
      wk, wqkvT + (size_t)KOFF * HIDW, HIDW, NKVH * HD);
  k_tr_cvt<<<dim3((NKVH * HD) / 32, HIDW / 32), 256, 0, stream>>>(
      wv, wqkvT + (size_t)VOFF * HIDW, HIDW, NKVH * HD);
  k_tr_cvt<<<dim3(HIDW / 32, KOFF / 32), 256, 0, stream>>>(wo, woT, KOFF, HIDW);
  // 3) QKV projection with FUSED rope (LDS-staged cos/sin; Q scaled for
  //    base-2 softmax); V stored plain bf16
  k_gemm256<2, 2><<<(MROWS / 256) * (QKVN / 256), 512, 0, stream>>>(
      xb, wqkvT, qkv, MROWS, QKVN, HIDW, QKVN / 256, cosT, sinT);
  // 4) V transpose (proven kernel)
  k_vt<<<dim3(S_LEN / 32, 4 * NKVH, NB), 256, 0, stream>>>(qkv, vtb);
  // 5) attention (ctx written into xb region — xb no longer needed)
  k_attn<<<32 * 32, 256, 0, stream>>>(qkv, vtb, xb);
  // 6) output projection -> f32 d_out (128x256 tile, 256 blocks = 100% fill)
  k_gemm256<0, 1><<<(MROWS / 128) * (HIDW / 256), 512, 0, stream>>>(
      xb, woT, d_out, MROWS, HIDW, KOFF, HIDW / 256, nullptr, nullptr);
}

// Round 16
// 201.414 us; speedup vs baseline: 1.0653x; 1.0653x over previous
//
#include <hip/hip_runtime.h>
#include <hip/hip_bf16.h>
#include <math.h>

#define S_LEN 2048
#define HIDW 2048
#define NHEAD 16
#define NKVH 4
#define HD 128
#define NB 2
#define MROWS (NB * S_LEN)                 // 4096
#define QKVN (NHEAD * HD + 2 * NKVH * HD)  // 3072
#define KOFF (NHEAD * HD)                  // 2048
#define VOFF (NHEAD * HD + NKVH * HD)      // 2560

typedef __bf16 bf16_t;
typedef __bf16 bf16x8_t __attribute__((ext_vector_type(8)));
typedef float f32x4_t __attribute__((ext_vector_type(4)));

__device__ __forceinline__ void gload_lds16(const bf16_t* g, bf16_t* l) {
  __builtin_amdgcn_global_load_lds(
      (const __attribute__((address_space(1))) void*)g,
      (__attribute__((address_space(3))) void*)l, 16, 0, 0);
}

__device__ __forceinline__ f32x4_t zero4() {
  f32x4_t z = {0.f, 0.f, 0.f, 0.f};
  return z;
}

__device__ __forceinline__ float fexp2(float x) {
#if __has_builtin(__builtin_amdgcn_exp2f)
  return __builtin_amdgcn_exp2f(x);
#else
  return exp2f(x);
#endif
}

// ---------------- convert x (f32 -> bf16), 8 elems/thread ----------------
__global__ __launch_bounds__(256) void k_cvt8(const float* __restrict__ in,
                                              bf16_t* __restrict__ out, int n8) {
  int i = blockIdx.x * 256 + threadIdx.x;
  if (i >= n8) return;
  const float4* p = (const float4*)(in + (size_t)i * 8);
  float4 a = p[0], b = p[1];
  bf16x8_t r;
  r[0] = (bf16_t)a.x; r[1] = (bf16_t)a.y; r[2] = (bf16_t)a.z; r[3] = (bf16_t)a.w;
  r[4] = (bf16_t)b.x; r[5] = (bf16_t)b.y; r[6] = (bf16_t)b.z; r[7] = (bf16_t)b.w;
  *(bf16x8_t*)(out + (size_t)i * 8) = r;
}

// ---------------- transpose + convert: in f32 [R][C] -> out bf16 [C][R] ----
__global__ __launch_bounds__(256) void k_tr_cvt(const float* __restrict__ in,
                                                bf16_t* __restrict__ out, int R, int C) {
  __shared__ float t[32][33];
  int c0 = blockIdx.x * 32, r0 = blockIdx.y * 32;
  int tx = threadIdx.x & 31, ty = threadIdx.x >> 5;
#pragma unroll
  for (int rr = ty; rr < 32; rr += 8) t[rr][tx] = in[(size_t)(r0 + rr) * C + c0 + tx];
  __syncthreads();
#pragma unroll
  for (int rr = ty; rr < 32; rr += 8)
    out[(size_t)(c0 + rr) * R + r0 + tx] = (bf16_t)t[tx][rr];
}

// ------------- QKV GEMM: 256x192 tile, 256 blocks = 100% CU fill -----------
// R13 counted-vmcnt 4-phase schedule, 7 granules/tile (A0..A3, B0..B2; one
// granule = 64 rows x 64 K = 8 KB = one block-wide global_load_lds).
// Ledger: P1 reads af0(8)+allB(6); P2 issues A0,A2 (freed P1), mfma af0xb2;
// P3 reads af1(8), issues B0,B1; P4 issues B2,A1,A3 (freed P3), mfma af1xb2.
// Boundary vmcnt(7): tile t+1 (issued during t-1) landed, t+2's 7 in flight.
// Fused epilogue: rope'd Q/K + plain V -> qkv; cos/sin staged in dead As LDS
// in TWO 128-row halves (As = 64 KB < 2x64 KB needed for all 256 rows).
__global__ __launch_bounds__(512, 2) void k_gemm_qkv(const bf16_t* __restrict__ A,
                                                     const bf16_t* __restrict__ Bt,
                                                     bf16_t* __restrict__ qkv,
                                                     const float* __restrict__ cosT,
                                                     const float* __restrict__ sinT) {
  __shared__ bf16_t As[2][256 * 64];   // 64 KB
  __shared__ bf16_t Bs[2][192 * 64];   // 48 KB
  const int K = HIDW;
  int tid = threadIdx.x;
  int lane = tid & 63, wid = tid >> 6;
  int l15 = lane & 15, lg = lane >> 4;
  int wrb = (wid >> 2) * 128;  // 0 or 128
  int wcb = (wid & 3) * 48;    // 0,48,96,144

  int nwg = gridDim.x;          // 256
  int qx = nwg >> 3;
  int lin = blockIdx.x;
  int wg = (lin & 7) * qx + (lin >> 3);
  int row0 = (wg >> 4) * 256, col0 = (wg & 15) * 192;

  int srow = tid >> 3;
  int scol = ((tid & 7) ^ (srow & 7)) * 8;
  const bf16_t* Ag = A + (size_t)(row0 + srow) * K + scol;
  const bf16_t* Bg = Bt + (size_t)(col0 + srow) * K + scol;

  f32x4_t acc[8][3];
#pragma unroll
  for (int i = 0; i < 8; i++)
#pragma unroll
    for (int j = 0; j < 3; j++) acc[i][j] = zero4();

  int xr = (l15 & 7) << 4;
  const int nk = K >> 6;  // 32

  auto stA = [&](int tt, int u) {
    gload_lds16(Ag + (size_t)u * 64 * K + (size_t)tt * 64, As[tt & 1] + u * 4096 + tid * 8);
  };
  auto stB = [&](int tt, int u) {
    gload_lds16(Bg + (size_t)u * 64 * K + (size_t)tt * 64, Bs[tt & 1] + u * 4096 + tid * 8);
  };

  // prologue: stage tiles 0,1; wait tile 0 (tile 1's 7 stay in flight)
  for (int tt = 0; tt < 2; tt++) {
    for (int u = 0; u < 4; u++) stA(tt, u);
    for (int u = 0; u < 3; u++) stB(tt, u);
  }
  asm volatile("s_waitcnt vmcnt(7)" ::: "memory");
  __builtin_amdgcn_s_barrier();
  __builtin_amdgcn_sched_barrier(0);

  for (int t = 0; t < nk; t++) {
    const char* Ac = (const char*)As[t & 1];
    const char* Bc = (const char*)Bs[t & 1];
    bool pf = (t + 2 < nk);

    // P1: reads af0 + ALL B; mfma af0 x {b0,b1}
    bf16x8_t af0[4][2], bfr[3][2];
#pragma unroll
    for (int i = 0; i < 4; i++) {
      int row = wrb + i * 16 + l15;
#pragma unroll
      for (int kk = 0; kk < 2; kk++)
        af0[i][kk] = *(const bf16x8_t*)(Ac + ((row * 128 + kk * 64 + lg * 16) ^ xr));
    }
#pragma unroll
    for (int j = 0; j < 3; j++) {
      int rowb = wcb + j * 16 + l15;
#pragma unroll
      for (int kk = 0; kk < 2; kk++)
        bfr[j][kk] = *(const bf16x8_t*)(Bc + ((rowb * 128 + kk * 64 + lg * 16) ^ xr));
    }
    __builtin_amdgcn_s_barrier();
    __builtin_amdgcn_s_setprio(1);
#pragma unroll
    for (int i = 0; i < 4; i++)
#pragma unroll
      for (int j = 0; j < 2; j++)
#pragma unroll
        for (int kk = 0; kk < 2; kk++)
          acc[i][j] = __builtin_amdgcn_mfma_f32_16x16x32_bf16(af0[i][kk], bfr[j][kk],
                                                              acc[i][j], 0, 0, 0);
    __builtin_amdgcn_s_setprio(0);

    // P2: issue A0,A2 (af0 granules, freed by P1's barrier); mfma af0 x b2
    if (pf) { stA(t + 2, 0); stA(t + 2, 2); }
    __builtin_amdgcn_s_barrier();
    __builtin_amdgcn_s_setprio(1);
#pragma unroll
    for (int i = 0; i < 4; i++)
#pragma unroll
      for (int kk = 0; kk < 2; kk++)
        acc[i][2] = __builtin_amdgcn_mfma_f32_16x16x32_bf16(af0[i][kk], bfr[2][kk],
                                                            acc[i][2], 0, 0, 0);
    __builtin_amdgcn_s_setprio(0);

    // P3: read af1; issue B0,B1 (read at P1); mfma af1 x {b0,b1}
    bf16x8_t af1[4][2];
#pragma unroll
    for (int i = 0; i < 4; i++) {
      int row = wrb + 64 + i * 16 + l15;
#pragma unroll
      for (int kk = 0; kk < 2; kk++)
        af1[i][kk] = *(const bf16x8_t*)(Ac + ((row * 128 + kk * 64 + lg * 16) ^ xr));
    }
    if (pf) { stB(t + 2, 0); stB(t + 2, 1); }
    __builtin_amdgcn_s_barrier();
    __builtin_amdgcn_s_setprio(1);
#pragma unroll
    for (int i = 0; i < 4; i++)
#pragma unroll
      for (int j = 0; j < 2; j++)
#pragma unroll
        for (int kk = 0; kk < 2; kk++)
          acc[4 + i][j] = __builtin_amdgcn_mfma_f32_16x16x32_bf16(
              af1[i][kk], bfr[j][kk], acc[4 + i][j], 0, 0, 0);
    __builtin_amdgcn_s_setprio(0);

    // P4: issue B2 + A1,A3 (af1 granules, freed by P3's barrier); mfma af1xb2
    if (pf) { stB(t + 2, 2); stA(t + 2, 1); stA(t + 2, 3); }
    __builtin_amdgcn_s_barrier();
    __builtin_amdgcn_s_setprio(1);
#pragma unroll
    for (int i = 0; i < 4; i++)
#pragma unroll
      for (int kk = 0; kk < 2; kk++)
        acc[4 + i][2] = __builtin_amdgcn_mfma_f32_16x16x32_bf16(
            af1[i][kk], bfr[2][kk], acc[4 + i][2], 0, 0, 0);
    __builtin_amdgcn_s_setprio(0);

    if (t + 1 < nk) {
      if (pf) asm volatile("s_waitcnt vmcnt(7)" ::: "memory");
      else    asm volatile("s_waitcnt vmcnt(0)" ::: "memory");
    }
    __builtin_amdgcn_s_barrier();
    __builtin_amdgcn_sched_barrier(0);
  }

  // ---- fused epilogue ----
  if (col0 < VOFF) {
    int sbase = row0 & (S_LEN - 1);
    const float QS = 0.08838834764831845f * 1.4426950408889634f;
#pragma unroll
    for (int hh = 0; hh < 2; hh++) {
      const float* cp = cosT + (size_t)(sbase + hh * 128) * 64;
      const float* sp = sinT + (size_t)(sbase + hh * 128) * 64;
#pragma unroll
      for (int k = 0; k < 4; k++) {
        gload_lds16((const bf16_t*)(cp + k * 2048 + (size_t)tid * 4),
                    As[0] + k * 4096 + tid * 8);
        gload_lds16((const bf16_t*)(sp + k * 2048 + (size_t)tid * 4),
                    As[1] + k * 4096 + tid * 8);
      }
      asm volatile("s_waitcnt vmcnt(0)" ::: "memory");
      __builtin_amdgcn_s_barrier();
      if ((wrb >> 7) == hh) {  // wave-uniform
        const float* cosF = (const float*)As[0];
        const float* sinF = (const float*)As[1];
#pragma unroll
        for (int i = 0; i < 8; i++) {
#pragma unroll
          for (int j = 0; j < 3; j++) {
            int c = col0 + wcb + j * 16 + l15;
            int rll = i * 16 + lg * 4;
            if (c < VOFF) {  // 16-col groups: no lane divergence (VOFF%16==0)
              float scale = (c < KOFF) ? QS : 1.0f;
              int p0 = (c & 127) >> 1;
              int codd = c & 1;
#pragma unroll
              for (int qd = 0; qd < 4; qd++) {
                float self = acc[i][j][qd];
                float other = __shfl_xor(self, 1);
                float cv = cosF[(rll + qd) * 64 + p0], sv = sinF[(rll + qd) * 64 + p0];
                float outv = codd ? (self * cv + other * sv) : (self * cv - other * sv);
                qkv[(size_t)(row0 + hh * 128 + rll + qd) * QKVN + c] =
                    (bf16_t)(outv * scale);
              }
            } else {
#pragma unroll
              for (int qd = 0; qd < 4; qd++)
                qkv[(size_t)(row0 + hh * 128 + rll + qd) * QKVN + c] =
                    (bf16_t)acc[i][j][qd];
            }
          }
        }
      }
      __builtin_amdgcn_s_barrier();  // protect As before next half's staging
    }
  } else {
    // pure-V block: plain bf16 stores (transpose by k_vt)
#pragma unroll
    for (int i = 0; i < 8; i++) {
#pragma unroll
      for (int j = 0; j < 3; j++) {
        int r = row0 + wrb + i * 16 + lg * 4;
        int c = col0 + wcb + j * 16 + l15;
#pragma unroll
        for (int qd = 0; qd < 4; qd++)
          qkv[(size_t)(r + qd) * QKVN + c] = (bf16_t)acc[i][j][qd];
      }
    }
  }
}

// ------------- out-proj GEMM: 128x256 tile (R13 counted schedule) ----------
__global__ __launch_bounds__(512, 2) void k_gemm_out(const bf16_t* __restrict__ A,
                                                     const bf16_t* __restrict__ Bt,
                                                     float* __restrict__ Cout) {
  __shared__ bf16_t As[2][128 * 64];
  __shared__ bf16_t Bs[2][256 * 64];
  const int K = KOFF;   // 2048
  const int N = HIDW;   // 2048
  int tid = threadIdx.x;
  int lane = tid & 63, wid = tid >> 6;
  int l15 = lane & 15, lg = lane >> 4;
  int wrb = (wid >> 2) * 64;
  int wcb = (wid & 3) * 64;

  int nwg = gridDim.x;  // 256
  int qx = nwg >> 3;
  int lin = blockIdx.x;
  int wg = (lin & 7) * qx + (lin >> 3);
  int row0 = (wg >> 3) * 128, col0 = (wg & 7) * 256;

  int srow = tid >> 3;
  int scol = ((tid & 7) ^ (srow & 7)) * 8;
  const bf16_t* Ag = A + (size_t)(row0 + srow) * K + scol;
  const bf16_t* Bg = Bt + (size_t)(col0 + srow) * K + scol;

  f32x4_t acc[4][4];
#pragma unroll
  for (int i = 0; i < 4; i++)
#pragma unroll
    for (int j = 0; j < 4; j++) acc[i][j] = zero4();

  int xr = (l15 & 7) << 4;
  const int nk = K >> 6;  // 32

  auto stA = [&](int tt, int u) {
    gload_lds16(Ag + (size_t)u * 64 * K + (size_t)tt * 64, As[tt & 1] + u * 4096 + tid * 8);
  };
  auto stB = [&](int tt, int u) {
    gload_lds16(Bg + (size_t)u * 64 * K + (size_t)tt * 64, Bs[tt & 1] + u * 4096 + tid * 8);
  };

  for (int tt = 0; tt < 2; tt++) {
    for (int u = 0; u < 2; u++) stA(tt, u);
    for (int u = 0; u < 4; u++) stB(tt, u);
  }
  asm volatile("s_waitcnt vmcnt(6)" ::: "memory");
  __builtin_amdgcn_s_barrier();
  __builtin_amdgcn_sched_barrier(0);

  for (int t = 0; t < nk; t++) {
    const char* Ac = (const char*)As[t & 1];
    const char* Bc = (const char*)Bs[t & 1];
    bool pf = (t + 2 < nk);

    bf16x8_t af0[4][2], bfr[4][2];
#pragma unroll
    for (int i = 0; i < 4; i++) {
      int row = wrb + i * 16 + l15;
#pragma unroll
      for (int kk = 0; kk < 2; kk++)
        af0[i][kk] = *(const bf16x8_t*)(Ac + ((row * 128 + kk * 64 + lg * 16) ^ xr));
    }
#pragma unroll
    for (int j = 0; j < 4; j++) {
      int rowb = wcb + j * 16 + l15;
#pragma unroll
      for (int kk = 0; kk < 2; kk++)
        bfr[j][kk] = *(const bf16x8_t*)(Bc + ((rowb * 128 + kk * 64 + lg * 16) ^ xr));
    }
    __builtin_amdgcn_s_barrier();
    __builtin_amdgcn_s_setprio(1);
#pragma unroll
    for (int i = 0; i < 4; i++)
#pragma unroll
      for (int kk = 0; kk < 2; kk++)
        acc[i][0] = __builtin_amdgcn_mfma_f32_16x16x32_bf16(af0[i][kk], bfr[0][kk],
                                                            acc[i][0], 0, 0, 0);
    __builtin_amdgcn_s_setprio(0);

    if (pf) { stA(t + 2, 0); stA(t + 2, 1); }
    __builtin_amdgcn_s_barrier();
    __builtin_amdgcn_s_setprio(1);
#pragma unroll
    for (int i = 0; i < 4; i++)
#pragma unroll
      for (int kk = 0; kk < 2; kk++)
        acc[i][1] = __builtin_amdgcn_mfma_f32_16x16x32_bf16(af0[i][kk], bfr[1][kk],
                                                            acc[i][1], 0, 0, 0);
    __builtin_amdgcn_s_setprio(0);

    if (pf) { stB(t + 2, 0); stB(t + 2, 1); }
    __builtin_amdgcn_s_barrier();
    __builtin_amdgcn_s_setprio(1);
#pragma unroll
    for (int i = 0; i < 4; i++)
#pragma unroll
      for (int kk = 0; kk < 2; kk++)
        acc[i][2] = __builtin_amdgcn_mfma_f32_16x16x32_bf16(af0[i][kk], bfr[2][kk],
                                                            acc[i][2], 0, 0, 0);
    __builtin_amdgcn_s_setprio(0);

    if (pf) { stB(t + 2, 2); stB(t + 2, 3); }
    __builtin_amdgcn_s_barrier();
    __builtin_amdgcn_s_setprio(1);
#pragma unroll
    for (int i = 0; i < 4; i++)
#pragma unroll
      for (int kk = 0; kk < 2; kk++)
        acc[i][3] = __builtin_amdgcn_mfma_f32_16x16x32_bf16(af0[i][kk], bfr[3][kk],
                                                            acc[i][3], 0, 0, 0);
    __builtin_amdgcn_s_setprio(0);

    if (t + 1 < nk) {
      if (pf) asm volatile("s_waitcnt vmcnt(6)" ::: "memory");
      else    asm volatile("s_waitcnt vmcnt(0)" ::: "memory");
    }
    __builtin_amdgcn_s_barrier();
    __builtin_amdgcn_sched_barrier(0);
  }

#pragma unroll
  for (int i = 0; i < 4; i++) {
#pragma unroll
    for (int j = 0; j < 4; j++) {
      int r = row0 + wrb + i * 16 + lg * 4;
      int c = col0 + wcb + j * 16 + l15;
#pragma unroll
      for (int qd = 0; qd < 4; qd++)
        Cout[(size_t)(r + qd) * N + c] = acc[i][j][qd];
    }
  }
}

// ---------------- V -> Vt relayout: vt[b][kvh][d][s] -----------------------
__global__ __launch_bounds__(256) void k_vt(const bf16_t* __restrict__ qkv,
                                            bf16_t* __restrict__ vt) {
  __shared__ bf16_t t[32][33];
  int s0 = blockIdx.x * 32;
  int dt = (blockIdx.y & 3) * 32;
  int h = blockIdx.y >> 2;
  int b = blockIdx.z;
  int tx = threadIdx.x & 31, ty = threadIdx.x >> 5;
#pragma unroll
  for (int rr = ty; rr < 32; rr += 8)
    t[rr][tx] = qkv[(size_t)(b * S_LEN + s0 + rr) * QKVN + VOFF + h * HD + dt + tx];
  __syncthreads();
#pragma unroll
  for (int rr = ty; rr < 32; rr += 8)
    vt[((size_t)((b * NKVH + h) * HD + dt + rr)) * S_LEN + s0 + tx] = t[tx][rr];
}

// ---------------- flash attention: 4 waves, QBLK=64, 2-phase pipeline ------
// R8 structure + swapped QK^T softmax (R12, verified): mfma(K,Q) -> per-lane
// q-row stats, 4 shuffles/tile instead of 32.
__global__ __launch_bounds__(256, 2) void k_attn(const bf16_t* __restrict__ qkv,
                                                 const bf16_t* __restrict__ vt,
                                                 bf16_t* __restrict__ ctx) {
  __shared__ bf16_t Ks[2 * 64 * 128];   // 2 x 16 KB, swizzled [kv][d]
  __shared__ bf16_t Vs[2 * 128 * 64];   // 2 x 16 KB, swizzled [d][kv]
  __shared__ bf16_t plds[4][16 * 72];

  int tid = threadIdx.x;
  int lane = tid & 63, wid = tid >> 6;
  int idx = blockIdx.x;
  int bh = idx & 31;
  int qg = 31 - (idx >> 5);        // longest-first dispatch (LPT backfill)
  int b = bh >> 4, h = bh & 15;
  int kvh = h >> 2;
  int q0 = qg * 64 + wid * 16;
  int l15 = lane & 15, lg = lane >> 4;

  const bf16_t* Kbase = qkv + (size_t)(b * S_LEN) * QKVN + KOFF + kvh * HD;
  const bf16_t* Vbase = vt + (size_t)(b * NKVH + kvh) * HD * S_LEN;

  const bf16_t* Qp = qkv + (size_t)(b * S_LEN + q0 + l15) * QKVN + h * HD + lg * 8;
  bf16x8_t aq[4];
#pragma unroll
  for (int kk = 0; kk < 4; kk++) aq[kk] = *(const bf16x8_t*)(Qp + kk * 32);

  int Ls[4], Lk[4], Lv[4];
#pragma unroll
  for (int u = 0; u < 4; u++) {
    int L = u * 4096 + tid * 16;
    Ls[u] = L >> 1;
    Lk[u] = L ^ (((L >> 8) & 7) << 4);
    Lv[u] = L ^ (((L >> 7) & 7) << 4);
  }

  f32x4_t o[8];
#pragma unroll
  for (int j = 0; j < 8; j++) o[j] = zero4();
  float ms = -INFINITY, lsum = 0.f;   // per-lane scalars: stats of q-row l15

  bf16_t* pbuf = &plds[wid][0];
  int xr = (l15 & 7) << 4;
  int ntiles = qg + 1;
  int qcol = q0 + l15;                // this lane's q-row

#pragma unroll
  for (int u = 0; u < 4; u++) {
    gload_lds16(Kbase + (size_t)(Lk[u] >> 8) * QKVN + ((Lk[u] & 255) >> 1), Ks + Ls[u]);
    gload_lds16(Vbase + (size_t)(Lv[u] >> 7) * S_LEN + ((Lv[u] & 127) >> 1), Vs + Ls[u]);
  }
  __syncthreads();

  for (int t = 0; t < ntiles; t++) {
    int kv0 = t * 64;
    if (t + 1 < ntiles) {
      const bf16_t* Kn = Kbase + (size_t)(kv0 + 64) * QKVN;
      const bf16_t* Vn = Vbase + kv0 + 64;
      int bo = ((t + 1) & 1) * 8192;
#pragma unroll
      for (int u = 0; u < 4; u++) {
        gload_lds16(Kn + (size_t)(Lk[u] >> 8) * QKVN + ((Lk[u] & 255) >> 1), Ks + bo + Ls[u]);
        gload_lds16(Vn + (size_t)(Lv[u] >> 7) * S_LEN + ((Lv[u] & 127) >> 1), Vs + bo + Ls[u]);
      }
    }
    const char* Kb = (const char*)Ks + (t & 1) * 16384;
    const char* Vb = (const char*)Vs + (t & 1) * 16384;

    // ---- QK^T swapped: sacc[cg][i] = S[kv = kv0+cg*16+lg*4+i][q = qcol] ----
    f32x4_t sacc[4];
#pragma unroll
    for (int cg = 0; cg < 4; cg++) sacc[cg] = zero4();
#pragma unroll
    for (int cg = 0; cg < 4; cg++) {
#pragma unroll
      for (int kk = 0; kk < 4; kk++) {
        int boff = ((cg * 16 + l15) * 256 + kk * 64 + lg * 16) ^ xr;
        bf16x8_t bk = *(const bf16x8_t*)(Kb + boff);
        sacc[cg] = __builtin_amdgcn_mfma_f32_16x16x32_bf16(bk, aq[kk], sacc[cg], 0, 0, 0);
      }
    }
    if (kv0 + 63 > q0) {
#pragma unroll
      for (int cg = 0; cg < 4; cg++) {
#pragma unroll
        for (int i = 0; i < 4; i++) {
          int kvg = kv0 + cg * 16 + lg * 4 + i;
          if (kvg > qcol) sacc[cg][i] = -1e30f;
        }
      }
    }
    // ---- online softmax: in-lane reduce + 2 shuffles ----
    float pmax = sacc[0][0];
#pragma unroll
    for (int cg = 0; cg < 4; cg++)
#pragma unroll
      for (int i = 0; i < 4; i++) pmax = fmaxf(pmax, sacc[cg][i]);
    pmax = fmaxf(pmax, __shfl_xor(pmax, 16));
    pmax = fmaxf(pmax, __shfl_xor(pmax, 32));
    if (__any(pmax - ms > 8.0f)) {
      float nm = fmaxf(ms, pmax);
      float sc = fexp2(ms - nm);
      ms = nm;
      lsum *= sc;
      float sci[4];
#pragma unroll
      for (int i = 0; i < 4; i++) sci[i] = __shfl(sc, lg * 4 + i);
#pragma unroll
      for (int j = 0; j < 8; j++)
#pragma unroll
        for (int i = 0; i < 4; i++) o[j][i] *= sci[i];
    }
    float ls = 0.f;
#pragma unroll
    for (int cg = 0; cg < 4; cg++)
#pragma unroll
      for (int i = 0; i < 4; i++) {
        sacc[cg][i] = fexp2(sacc[cg][i] - ms);
        ls += sacc[cg][i];
      }
    ls += __shfl_xor(ls, 16);
    ls += __shfl_xor(ls, 32);
    lsum += ls;
    // ---- P -> per-wave LDS (row = q = l15) ----
#pragma unroll
    for (int cg = 0; cg < 4; cg++)
#pragma unroll
      for (int i = 0; i < 4; i++)
        pbuf[l15 * 72 + cg * 16 + lg * 4 + i] = (bf16_t)sacc[cg][i];
    __builtin_amdgcn_wave_barrier();
    bf16x8_t pa0 = *(const bf16x8_t*)(pbuf + l15 * 72 + lg * 8);
    bf16x8_t pa1 = *(const bf16x8_t*)(pbuf + l15 * 72 + 32 + lg * 8);
    __builtin_amdgcn_wave_barrier();
#pragma unroll
    for (int j = 0; j < 8; j++) {
      int d = j * 16 + l15;
      int bo0 = (d * 128 + lg * 16) ^ xr;
      int bo1 = (d * 128 + 64 + lg * 16) ^ xr;
      o[j] = __builtin_amdgcn_mfma_f32_16x16x32_bf16(
          pa0, *(const bf16x8_t*)(Vb + bo0), o[j], 0, 0, 0);
      o[j] = __builtin_amdgcn_mfma_f32_16x16x32_bf16(
          pa1, *(const bf16x8_t*)(Vb + bo1), o[j], 0, 0, 0);
    }
    __syncthreads();
  }

  bf16_t* Cp = ctx + (size_t)(b * S_LEN + q0) * KOFF + h * HD;
#pragma unroll
  for (int i = 0; i < 4; i++) {
    float inv = 1.f / __shfl(lsum, lg * 4 + i);
    int row = lg * 4 + i;
#pragma unroll
    for (int j = 0; j < 8; j++)
      Cp[(size_t)row * KOFF + j * 16 + l15] = (bf16_t)(o[j][i] * inv);
  }
}

extern "C" void kernel_launch(void* const* d_in, const int* in_sizes, int n_in,
                              void* d_out, int out_size, void* d_ws, size_t ws_size,
                              hipStream_t stream) {
  const float* x = (const float*)d_in[0];
  const float* wq = (const float*)d_in[1];
  const float* wk = (const float*)d_in[2];
  const float* wv = (const float*)d_in[3];
  const float* wo = (const float*)d_in[4];
  const float* cosT = (const float*)d_in[5];
  const float* sinT = (const float*)d_in[6];

  bf16_t* xb = (bf16_t*)d_ws;                          // 4096x2048 (later reused as ctx)
  bf16_t* wqkvT = xb + (size_t)MROWS * HIDW;           // 3072x2048
  bf16_t* woT = wqkvT + (size_t)QKVN * HIDW;           // 2048x2048
  bf16_t* qkv = woT + (size_t)HIDW * HIDW;             // 4096x3072
  bf16_t* vtb = qkv + (size_t)MROWS * QKVN;            // 2*4*128*2048

  // 1) convert x
  k_cvt8<<<MROWS * HIDW / 8 / 256, 256, 0, stream>>>(x, xb, MROWS * HIDW / 8);
  // 2) weight transposes (f32 -> bf16, [K][N] -> [N][K])
  k_tr_cvt<<<dim3(KOFF / 32, HIDW / 32), 256, 0, stream>>>(wq, wqkvT, HIDW, KOFF);
  k_tr_cvt<<<dim3((NKVH * HD) / 32, HIDW / 32), 256, 0, stream>>>(
      wk, wqkvT + (size_t)KOFF * HIDW, HIDW, NKVH * HD);
  k_tr_cvt<<<dim3((NKVH * HD) / 32, HIDW / 32), 256, 0, stream>>>(
      wv, wqkvT + (size_t)VOFF * HIDW, HIDW, NKVH * HD);
  k_tr_cvt<<<dim3(HIDW / 32, KOFF / 32), 256, 0, stream>>>(wo, woT, KOFF, HIDW);
  // 3) QKV projection, 256x192 tile -> 256 blocks = 100% CU fill; fused rope
  k_gemm_qkv<<<(MROWS / 256) * (QKVN / 192), 512, 0, stream>>>(
      xb, wqkvT, qkv, cosT, sinT);
  // 4) V transpose
  k_vt<<<dim3(S_LEN / 32, 4 * NKVH, NB), 256, 0, stream>>>(qkv, vtb);
  // 5) attention (ctx written into xb region — xb no longer needed)
  k_attn<<<32 * 32, 256, 0, stream>>>(qkv, vtb, xb);
  // 6) output projection -> f32 d_out (128x256 tile, 256 blocks = 100% fill)
  k_gemm_out<<<(MROWS / 128) * (HIDW / 256), 512, 0, stream>>>(xb, woT,
                                                               (float*)d_out);
}

// Round 17
// 198.944 us; speedup vs baseline: 1.0785x; 1.0124x over previous
//
#include <hip/hip_runtime.h>
#include <hip/hip_bf16.h>
#include <math.h>

#define S_LEN 2048
#define HIDW 2048
#define NHEAD 16
#define NKVH 4
#define HD 128
#define NB 2
#define MROWS (NB * S_LEN)                 // 4096
#define QKVN (NHEAD * HD + 2 * NKVH * HD)  // 3072
#define KOFF (NHEAD * HD)                  // 2048
#define VOFF (NHEAD * HD + NKVH * HD)      // 2560

typedef __bf16 bf16_t;
typedef __bf16 bf16x8_t __attribute__((ext_vector_type(8)));
typedef float f32x4_t __attribute__((ext_vector_type(4)));

__device__ __forceinline__ void gload_lds16(const bf16_t* g, bf16_t* l) {
  __builtin_amdgcn_global_load_lds(
      (const __attribute__((address_space(1))) void*)g,
      (__attribute__((address_space(3))) void*)l, 16, 0, 0);
}

__device__ __forceinline__ f32x4_t zero4() {
  f32x4_t z = {0.f, 0.f, 0.f, 0.f};
  return z;
}

__device__ __forceinline__ float fexp2(float x) {
#if __has_builtin(__builtin_amdgcn_exp2f)
  return __builtin_amdgcn_exp2f(x);
#else
  return exp2f(x);
#endif
}

// ---------------- convert x (f32 -> bf16), 8 elems/thread ----------------
__global__ __launch_bounds__(256) void k_cvt8(const float* __restrict__ in,
                                              bf16_t* __restrict__ out, int n8) {
  int i = blockIdx.x * 256 + threadIdx.x;
  if (i >= n8) return;
  const float4* p = (const float4*)(in + (size_t)i * 8);
  float4 a = p[0], b = p[1];
  bf16x8_t r;
  r[0] = (bf16_t)a.x; r[1] = (bf16_t)a.y; r[2] = (bf16_t)a.z; r[3] = (bf16_t)a.w;
  r[4] = (bf16_t)b.x; r[5] = (bf16_t)b.y; r[6] = (bf16_t)b.z; r[7] = (bf16_t)b.w;
  *(bf16x8_t*)(out + (size_t)i * 8) = r;
}

// ---------------- transpose + convert: in f32 [R][C] -> out bf16 [C][R] ----
__global__ __launch_bounds__(256) void k_tr_cvt(const float* __restrict__ in,
                                                bf16_t* __restrict__ out, int R, int C) {
  __shared__ float t[32][33];
  int c0 = blockIdx.x * 32, r0 = blockIdx.y * 32;
  int tx = threadIdx.x & 31, ty = threadIdx.x >> 5;
#pragma unroll
  for (int rr = ty; rr < 32; rr += 8) t[rr][tx] = in[(size_t)(r0 + rr) * C + c0 + tx];
  __syncthreads();
#pragma unroll
  for (int rr = ty; rr < 32; rr += 8)
    out[(size_t)(c0 + rr) * R + r0 + tx] = (bf16_t)t[tx][rr];
}

// ---------------- GEMM BMx256 tile (BM = BMH*128), BK=64, 8 waves ----------
// R13 counted-vmcnt 4-phase schedule (best measured of 6 variants: 94 us).
// EPI=0: f32 out. EPI=2: fused rope epilogue (cos/sin staged in dead LDS).
template <int EPI, int BMH>
__global__ __launch_bounds__(512, 2) void k_gemm256(const bf16_t* __restrict__ A,
                                                    const bf16_t* __restrict__ Bt,
                                                    void* __restrict__ Cout,
                                                    int M, int N, int K, int nby,
                                                    const float* __restrict__ cosT,
                                                    const float* __restrict__ sinT) {
  __shared__ bf16_t As[2][BMH * 128 * 64];
  __shared__ bf16_t Bs[2][256 * 64];

  int tid = threadIdx.x;
  int lane = tid & 63, wid = tid >> 6;
  int l15 = lane & 15, lg = lane >> 4;
  int wrb = (wid >> 2) * (BMH * 64);
  int wcb = (wid & 3) * 64;

  int nwg = gridDim.x;
  int qx = nwg >> 3;
  int lin = blockIdx.x;
  int wg = (lin & 7) * qx + (lin >> 3);
  int row0 = (wg / nby) * (BMH * 128), col0 = (wg % nby) * 256;

  int srow = tid >> 3;
  int scol = ((tid & 7) ^ (srow & 7)) * 8;
  const bf16_t* Ag = A + (size_t)(row0 + srow) * K + scol;
  const bf16_t* Bg = Bt + (size_t)(col0 + srow) * K + scol;

  f32x4_t acc[BMH * 4][4];
#pragma unroll
  for (int i = 0; i < BMH * 4; i++)
#pragma unroll
    for (int j = 0; j < 4; j++) acc[i][j] = zero4();

  int xr = (l15 & 7) << 4;
  int nk = K >> 6;

  auto stA = [&](int tt, int u) {
    gload_lds16(Ag + (size_t)u * 64 * K + (size_t)tt * 64,
                As[tt & 1] + u * 4096 + tid * 8);
  };
  auto stB = [&](int tt, int u) {
    gload_lds16(Bg + (size_t)u * 64 * K + (size_t)tt * 64,
                Bs[tt & 1] + u * 4096 + tid * 8);
  };

  // prologue: stage tiles 0 and 1 fully; wait tile 0 (tile 1 stays in flight)
  for (int tt = 0; tt < 2 && tt < nk; tt++) {
    for (int u = 0; u < BMH * 2; u++) stA(tt, u);
    for (int u = 0; u < 4; u++) stB(tt, u);
  }
  if (nk > 1) {
    if constexpr (BMH == 2) asm volatile("s_waitcnt vmcnt(8)" ::: "memory");
    else asm volatile("s_waitcnt vmcnt(6)" ::: "memory");
  } else {
    asm volatile("s_waitcnt vmcnt(0)" ::: "memory");
  }
  __builtin_amdgcn_s_barrier();
  __builtin_amdgcn_sched_barrier(0);

  for (int t = 0; t < nk; t++) {
    const char* Ac = (const char*)As[t & 1];
    const char* Bc = (const char*)Bs[t & 1];
    bool pf = (t + 2 < nk);

    // P1: ds_read af0 + ALL B-frags; MFMA (mh0, nh0)
    bf16x8_t af0[4][2], bfr[4][2];
#pragma unroll
    for (int i = 0; i < 4; i++) {
      int row = wrb + i * 16 + l15;
#pragma unroll
      for (int kk = 0; kk < 2; kk++)
        af0[i][kk] = *(const bf16x8_t*)(Ac + ((row * 128 + kk * 64 + lg * 16) ^ xr));
    }
#pragma unroll
    for (int jn = 0; jn < 4; jn++) {
      int rowb = wcb + jn * 16 + l15;
#pragma unroll
      for (int kk = 0; kk < 2; kk++)
        bfr[jn][kk] = *(const bf16x8_t*)(Bc + ((rowb * 128 + kk * 64 + lg * 16) ^ xr));
    }
    __builtin_amdgcn_s_barrier();
    __builtin_amdgcn_s_setprio(1);
    if constexpr (BMH == 2) {
#pragma unroll
      for (int i = 0; i < 4; i++)
#pragma unroll
        for (int j = 0; j < 2; j++)
#pragma unroll
          for (int kk = 0; kk < 2; kk++)
            acc[i][j] = __builtin_amdgcn_mfma_f32_16x16x32_bf16(af0[i][kk], bfr[j][kk],
                                                                acc[i][j], 0, 0, 0);
    } else {
#pragma unroll
      for (int i = 0; i < 4; i++)
#pragma unroll
        for (int kk = 0; kk < 2; kk++)
          acc[i][0] = __builtin_amdgcn_mfma_f32_16x16x32_bf16(af0[i][kk], bfr[0][kk],
                                                              acc[i][0], 0, 0, 0);
    }
    __builtin_amdgcn_s_setprio(0);

    // P2: issue A granules freed at P1; MFMA (mh0, nh1)
    if (pf) {
      stA(t + 2, 0);
      if constexpr (BMH == 2) stA(t + 2, 2);
      else stA(t + 2, 1);
    }
    __builtin_amdgcn_s_barrier();
    __builtin_amdgcn_s_setprio(1);
    if constexpr (BMH == 2) {
#pragma unroll
      for (int i = 0; i < 4; i++)
#pragma unroll
        for (int j = 0; j < 2; j++)
#pragma unroll
          for (int kk = 0; kk < 2; kk++)
            acc[i][2 + j] = __builtin_amdgcn_mfma_f32_16x16x32_bf16(
                af0[i][kk], bfr[2 + j][kk], acc[i][2 + j], 0, 0, 0);
    } else {
#pragma unroll
      for (int i = 0; i < 4; i++)
#pragma unroll
        for (int kk = 0; kk < 2; kk++)
          acc[i][1] = __builtin_amdgcn_mfma_f32_16x16x32_bf16(af0[i][kk], bfr[1][kk],
                                                              acc[i][1], 0, 0, 0);
    }
    __builtin_amdgcn_s_setprio(0);

    // P3: (BMH=2) ds_read af1; issue B0,B1; MFMA
    bf16x8_t af1[4][2];
    if constexpr (BMH == 2) {
#pragma unroll
      for (int i = 0; i < 4; i++) {
        int row = wrb + 64 + i * 16 + l15;
#pragma unroll
        for (int kk = 0; kk < 2; kk++)
          af1[i][kk] = *(const bf16x8_t*)(Ac + ((row * 128 + kk * 64 + lg * 16) ^ xr));
      }
    }
    if (pf) { stB(t + 2, 0); stB(t + 2, 1); }
    __builtin_amdgcn_s_barrier();
    __builtin_amdgcn_s_setprio(1);
    if constexpr (BMH == 2) {
#pragma unroll
      for (int i = 0; i < 4; i++)
#pragma unroll
        for (int j = 0; j < 2; j++)
#pragma unroll
          for (int kk = 0; kk < 2; kk++)
            acc[4 + i][j] = __builtin_amdgcn_mfma_f32_16x16x32_bf16(
                af1[i][kk], bfr[j][kk], acc[4 + i][j], 0, 0, 0);
    } else {
#pragma unroll
      for (int i = 0; i < 4; i++)
#pragma unroll
        for (int kk = 0; kk < 2; kk++)
          acc[i][2] = __builtin_amdgcn_mfma_f32_16x16x32_bf16(af0[i][kk], bfr[2][kk],
                                                              acc[i][2], 0, 0, 0);
    }
    __builtin_amdgcn_s_setprio(0);

    // P4: issue B2,B3 (+A1,A3 for BMH=2); MFMA
    if (pf) {
      stB(t + 2, 2); stB(t + 2, 3);
      if constexpr (BMH == 2) { stA(t + 2, 1); stA(t + 2, 3); }
    }
    __builtin_amdgcn_s_barrier();
    __builtin_amdgcn_s_setprio(1);
    if constexpr (BMH == 2) {
#pragma unroll
      for (int i = 0; i < 4; i++)
#pragma unroll
        for (int j = 0; j < 2; j++)
#pragma unroll
          for (int kk = 0; kk < 2; kk++)
            acc[4 + i][2 + j] = __builtin_amdgcn_mfma_f32_16x16x32_bf16(
                af1[i][kk], bfr[2 + j][kk], acc[4 + i][2 + j], 0, 0, 0);
    } else {
#pragma unroll
      for (int i = 0; i < 4; i++)
#pragma unroll
        for (int kk = 0; kk < 2; kk++)
          acc[i][3] = __builtin_amdgcn_mfma_f32_16x16x32_bf16(af0[i][kk], bfr[3][kk],
                                                              acc[i][3], 0, 0, 0);
    }
    __builtin_amdgcn_s_setprio(0);

    // boundary: counted wait (t+2's loads stay in flight)
    if (t + 1 < nk) {
      if (pf) {
        if constexpr (BMH == 2) asm volatile("s_waitcnt vmcnt(8)" ::: "memory");
        else asm volatile("s_waitcnt vmcnt(6)" ::: "memory");
      } else {
        asm volatile("s_waitcnt vmcnt(0)" ::: "memory");
      }
    }
    __builtin_amdgcn_s_barrier();
    __builtin_amdgcn_sched_barrier(0);
  }

  if (EPI == 2) {
    if (col0 < VOFF) {
      // stage cos/sin rows [sbase, sbase+256) x 64 f32 into dead As/Bs LDS
      int sbase = row0 & (S_LEN - 1);
      bf16_t* cosL = &As[0][0];
      bf16_t* sinL = &Bs[0][0];
#pragma unroll
      for (int k = 0; k < 8; k++) {
        gload_lds16((const bf16_t*)(cosT + (size_t)sbase * 64 + k * 2048 + tid * 4),
                    cosL + k * 4096 + tid * 8);
        gload_lds16((const bf16_t*)(sinT + (size_t)sbase * 64 + k * 2048 + tid * 4),
                    sinL + k * 4096 + tid * 8);
      }
      asm volatile("s_waitcnt vmcnt(0)" ::: "memory");
      __builtin_amdgcn_s_barrier();
      const float* cosF = (const float*)cosL;
      const float* sinF = (const float*)sinL;
      const float QS = 0.08838834764831845f * 1.4426950408889634f;
#pragma unroll
      for (int i = 0; i < BMH * 4; i++) {
#pragma unroll
        for (int j = 0; j < 4; j++) {
          int c = col0 + wcb + j * 16 + l15;
          int rlb = wrb + i * 16 + lg * 4;
          float scale = (c < KOFF) ? QS : 1.0f;
          int p0 = (c & 127) >> 1;
          int codd = c & 1;
#pragma unroll
          for (int qd = 0; qd < 4; qd++) {
            int rl = rlb + qd;
            float self = acc[i][j][qd];
            float other = __shfl_xor(self, 1);
            float cv = cosF[rl * 64 + p0], sv = sinF[rl * 64 + p0];
            float outv = codd ? (self * cv + other * sv) : (self * cv - other * sv);
            ((bf16_t*)Cout)[(size_t)(row0 + rl) * N + c] = (bf16_t)(outv * scale);
          }
        }
      }
    } else {
      // pure-V block: plain bf16 store (transpose done by k_vt)
#pragma unroll
      for (int i = 0; i < BMH * 4; i++) {
#pragma unroll
        for (int j = 0; j < 4; j++) {
          int r = row0 + wrb + i * 16 + lg * 4;
          int c = col0 + wcb + j * 16 + l15;
#pragma unroll
          for (int qd = 0; qd < 4; qd++)
            ((bf16_t*)Cout)[(size_t)(r + qd) * N + c] = (bf16_t)acc[i][j][qd];
        }
      }
    }
  } else {
#pragma unroll
    for (int i = 0; i < BMH * 4; i++) {
#pragma unroll
      for (int j = 0; j < 4; j++) {
        int r = row0 + wrb + i * 16 + lg * 4;
        int c = col0 + wcb + j * 16 + l15;
#pragma unroll
        for (int qd = 0; qd < 4; qd++)
          ((float*)Cout)[(size_t)(r + qd) * N + c] = acc[i][j][qd];
      }
    }
  }
}

// ---------------- V -> Vt relayout: vt[b][kvh][d][s] -----------------------
__global__ __launch_bounds__(256) void k_vt(const bf16_t* __restrict__ qkv,
                                            bf16_t* __restrict__ vt) {
  __shared__ bf16_t t[32][33];
  int s0 = blockIdx.x * 32;
  int dt = (blockIdx.y & 3) * 32;
  int h = blockIdx.y >> 2;
  int b = blockIdx.z;
  int tx = threadIdx.x & 31, ty = threadIdx.x >> 5;
#pragma unroll
  for (int rr = ty; rr < 32; rr += 8)
    t[rr][tx] = qkv[(size_t)(b * S_LEN + s0 + rr) * QKVN + VOFF + h * HD + dt + tx];
  __syncthreads();
#pragma unroll
  for (int rr = ty; rr < 32; rr += 8)
    vt[((size_t)((b * NKVH + h) * HD + dt + rr)) * S_LEN + s0 + tx] = t[tx][rr];
}

// ---------------- flash attention: 8 waves, QBLK=128, 2-phase pipeline -----
// Tile-amortization: per (b,h) the staged-KV-tile count halves vs QBLK=64
// (each stage serves 2x the MFMA); one granule = 512 thr x 16B = 8 KB = one
// block-wide global_load_lds -> 4 DMAs/tile (was 8). LDS 82 KB -> 1 block/CU
// (8 waves/CU, same waves/SIMD as 2x4-wave before). Dbuf prefetch stays a
// full tile ahead (R9 single-buffer trap avoided). Grid 512 blocks, LPT
// order (qg=15-idx>>5): 2 scheduling rounds, greedy backfill pairs long
// blocks with short -> per-CU ~34 tile-units. Swapped QK^T softmax (R12).
__global__ __launch_bounds__(512, 1) void k_attn(const bf16_t* __restrict__ qkv,
                                                 const bf16_t* __restrict__ vt,
                                                 bf16_t* __restrict__ ctx) {
  __shared__ bf16_t Ks[2 * 64 * 128];   // 2 x 16 KB, swizzled [kv][d]
  __shared__ bf16_t Vs[2 * 128 * 64];   // 2 x 16 KB, swizzled [d][kv]
  __shared__ bf16_t plds[8][16 * 72];   // 18 KB

  int tid = threadIdx.x;
  int lane = tid & 63, wid = tid >> 6;   // 8 waves
  int idx = blockIdx.x;
  int bh = idx & 31;
  int qg = 15 - (idx >> 5);        // longest-first dispatch (LPT backfill)
  int b = bh >> 4, h = bh & 15;
  int kvh = h >> 2;
  int q0 = qg * 128 + wid * 16;    // wave's 16 q-rows
  int l15 = lane & 15, lg = lane >> 4;

  const bf16_t* Kbase = qkv + (size_t)(b * S_LEN) * QKVN + KOFF + kvh * HD;
  const bf16_t* Vbase = vt + (size_t)(b * NKVH + kvh) * HD * S_LEN;

  const bf16_t* Qp = qkv + (size_t)(b * S_LEN + q0 + l15) * QKVN + h * HD + lg * 8;
  bf16x8_t aq[4];
#pragma unroll
  for (int kk = 0; kk < 4; kk++) aq[kk] = *(const bf16x8_t*)(Qp + kk * 32);

  // staging: granule u covers bytes [u*8192, u*8192+8192) of the 16 KB tile
  int Ls[2], Lk[2], Lv[2];
#pragma unroll
  for (int u = 0; u < 2; u++) {
    int L = u * 8192 + tid * 16;
    Ls[u] = L >> 1;
    Lk[u] = L ^ (((L >> 8) & 7) << 4);   // K rows: 256 B stride
    Lv[u] = L ^ (((L >> 7) & 7) << 4);   // V rows: 128 B stride
  }

  f32x4_t o[8];
#pragma unroll
  for (int j = 0; j < 8; j++) o[j] = zero4();
  float ms = -INFINITY, lsum = 0.f;   // per-lane scalars: stats of q-row l15

  bf16_t* pbuf = &plds[wid][0];
  int xr = (l15 & 7) << 4;
  int ntiles = 2 * qg + 2;
  int qcol = q0 + l15;                // this lane's q-row

#pragma unroll
  for (int u = 0; u < 2; u++) {
    gload_lds16(Kbase + (size_t)(Lk[u] >> 8) * QKVN + ((Lk[u] & 255) >> 1), Ks + Ls[u]);
    gload_lds16(Vbase + (size_t)(Lv[u] >> 7) * S_LEN + ((Lv[u] & 127) >> 1), Vs + Ls[u]);
  }
  __syncthreads();

  for (int t = 0; t < ntiles; t++) {
    int kv0 = t * 64;
    if (t + 1 < ntiles) {
      const bf16_t* Kn = Kbase + (size_t)(kv0 + 64) * QKVN;
      const bf16_t* Vn = Vbase + kv0 + 64;
      int bo = ((t + 1) & 1) * 8192;
#pragma unroll
      for (int u = 0; u < 2; u++) {
        gload_lds16(Kn + (size_t)(Lk[u] >> 8) * QKVN + ((Lk[u] & 255) >> 1), Ks + bo + Ls[u]);
        gload_lds16(Vn + (size_t)(Lv[u] >> 7) * S_LEN + ((Lv[u] & 127) >> 1), Vs + bo + Ls[u]);
      }
    }
    // wave-uniform skip: tiles fully above this wave's rows (early waves'
    // tail tile). Barriers stay outside the guard (all waves reach them).
    if (kv0 <= q0 + 15) {
      const char* Kb = (const char*)Ks + (t & 1) * 16384;
      const char* Vb = (const char*)Vs + (t & 1) * 16384;

      // ---- QK^T swapped: sacc[cg][i] = S[kv=kv0+cg*16+lg*4+i][q=qcol] ----
      f32x4_t sacc[4];
#pragma unroll
      for (int cg = 0; cg < 4; cg++) sacc[cg] = zero4();
#pragma unroll
      for (int cg = 0; cg < 4; cg++) {
#pragma unroll
        for (int kk = 0; kk < 4; kk++) {
          int boff = ((cg * 16 + l15) * 256 + kk * 64 + lg * 16) ^ xr;
          bf16x8_t bk = *(const bf16x8_t*)(Kb + boff);
          sacc[cg] = __builtin_amdgcn_mfma_f32_16x16x32_bf16(bk, aq[kk], sacc[cg], 0, 0, 0);
        }
      }
      if (kv0 + 63 > q0) {
#pragma unroll
        for (int cg = 0; cg < 4; cg++) {
#pragma unroll
          for (int i = 0; i < 4; i++) {
            int kvg = kv0 + cg * 16 + lg * 4 + i;
            if (kvg > qcol) sacc[cg][i] = -1e30f;
          }
        }
      }
      // ---- online softmax: in-lane reduce + 2 shuffles ----
      float pmax = sacc[0][0];
#pragma unroll
      for (int cg = 0; cg < 4; cg++)
#pragma unroll
        for (int i = 0; i < 4; i++) pmax = fmaxf(pmax, sacc[cg][i]);
      pmax = fmaxf(pmax, __shfl_xor(pmax, 16));
      pmax = fmaxf(pmax, __shfl_xor(pmax, 32));
      if (__any(pmax - ms > 8.0f)) {
        float nm = fmaxf(ms, pmax);
        float sc = fexp2(ms - nm);
        ms = nm;
        lsum *= sc;
        float sci[4];
#pragma unroll
        for (int i = 0; i < 4; i++) sci[i] = __shfl(sc, lg * 4 + i);
#pragma unroll
        for (int j = 0; j < 8; j++)
#pragma unroll
          for (int i = 0; i < 4; i++) o[j][i] *= sci[i];
      }
      float ls = 0.f;
#pragma unroll
      for (int cg = 0; cg < 4; cg++)
#pragma unroll
        for (int i = 0; i < 4; i++) {
          sacc[cg][i] = fexp2(sacc[cg][i] - ms);
          ls += sacc[cg][i];
        }
      ls += __shfl_xor(ls, 16);
      ls += __shfl_xor(ls, 32);
      lsum += ls;
      // ---- P -> per-wave LDS (row = q = l15) ----
#pragma unroll
      for (int cg = 0; cg < 4; cg++)
#pragma unroll
        for (int i = 0; i < 4; i++)
          pbuf[l15 * 72 + cg * 16 + lg * 4 + i] = (bf16_t)sacc[cg][i];
      __builtin_amdgcn_wave_barrier();
      bf16x8_t pa0 = *(const bf16x8_t*)(pbuf + l15 * 72 + lg * 8);
      bf16x8_t pa1 = *(const bf16x8_t*)(pbuf + l15 * 72 + 32 + lg * 8);
      __builtin_amdgcn_wave_barrier();
#pragma unroll
      for (int j = 0; j < 8; j++) {
        int d = j * 16 + l15;
        int bo0 = (d * 128 + lg * 16) ^ xr;
        int bo1 = (d * 128 + 64 + lg * 16) ^ xr;
        o[j] = __builtin_amdgcn_mfma_f32_16x16x32_bf16(
            pa0, *(const bf16x8_t*)(Vb + bo0), o[j], 0, 0, 0);
        o[j] = __builtin_amdgcn_mfma_f32_16x16x32_bf16(
            pa1, *(const bf16x8_t*)(Vb + bo1), o[j], 0, 0, 0);
      }
    }
    __syncthreads();
  }

  bf16_t* Cp = ctx + (size_t)(b * S_LEN + q0) * KOFF + h * HD;
#pragma unroll
  for (int i = 0; i < 4; i++) {
    float inv = 1.f / __shfl(lsum, lg * 4 + i);
    int row = lg * 4 + i;
#pragma unroll
    for (int j = 0; j < 8; j++)
      Cp[(size_t)row * KOFF + j * 16 + l15] = (bf16_t)(o[j][i] * inv);
  }
}

extern "C" void kernel_launch(void* const* d_in, const int* in_sizes, int n_in,
                              void* d_out, int out_size, void* d_ws, size_t ws_size,
                              hipStream_t stream) {
  const float* x = (const float*)d_in[0];
  const float* wq = (const float*)d_in[1];
  const float* wk = (const float*)d_in[2];
  const float* wv = (const float*)d_in[3];
  const float* wo = (const float*)d_in[4];
  const float* cosT = (const float*)d_in[5];
  const float* sinT = (const float*)d_in[6];

  bf16_t* xb = (bf16_t*)d_ws;                          // 4096x2048 (later reused as ctx)
  bf16_t* wqkvT = xb + (size_t)MROWS * HIDW;           // 3072x2048
  bf16_t* woT = wqkvT + (size_t)QKVN * HIDW;           // 2048x2048
  bf16_t* qkv = woT + (size_t)HIDW * HIDW;             // 4096x3072
  bf16_t* vtb = qkv + (size_t)MROWS * QKVN;            // 2*4*128*2048

  // 1) convert x
  k_cvt8<<<MROWS * HIDW / 8 / 256, 256, 0, stream>>>(x, xb, MROWS * HIDW / 8);
  // 2) weight transposes (f32 -> bf16, [K][N] -> [N][K])
  k_tr_cvt<<<dim3(KOFF / 32, HIDW / 32), 256, 0, stream>>>(wq, wqkvT, HIDW, KOFF);
  k_tr_cvt<<<dim3((NKVH * HD) / 32, HIDW / 32), 256, 0, stream>>>(
      wk, wqkvT + (size_t)KOFF * HIDW, HIDW, NKVH * HD);
  k_tr_cvt<<<dim3((NKVH * HD) / 32, HIDW / 32), 256, 0, stream>>>(
      wv, wqkvT + (size_t)VOFF * HIDW, HIDW, NKVH * HD);
  k_tr_cvt<<<dim3(HIDW / 32, KOFF / 32), 256, 0, stream>>>(wo, woT, KOFF, HIDW);
  // 3) QKV projection (R13 best-measured: 256x256, 192 blocks) + fused rope
  k_gemm256<2, 2><<<(MROWS / 256) * (QKVN / 256), 512, 0, stream>>>(
      xb, wqkvT, qkv, MROWS, QKVN, HIDW, QKVN / 256, cosT, sinT);
  // 4) V transpose
  k_vt<<<dim3(S_LEN / 32, 4 * NKVH, NB), 256, 0, stream>>>(qkv, vtb);
  // 5) attention, QBLK=128 x 8 waves (ctx -> xb region)
  k_attn<<<32 * 16, 512, 0, stream>>>(qkv, vtb, xb);
  // 6) output projection -> f32 d_out (128x256 tile, 256 blocks = 100% fill)
  k_gemm256<0, 1><<<(MROWS / 128) * (HIDW / 256), 512, 0, stream>>>(
      xb, woT, d_out, MROWS, HIDW, KOFF, HIDW / 256, nullptr, nullptr);
}